// Round 8
// baseline (155.431 us; speedup 1.0000x reference)
//
#include <hip/hip_runtime.h>
#include <math.h>

#define DD 64
#define LL 2048
#define NHEADS 32
#define NTHREADS 512
// main kernel tiling
#define TQ 64
#define TK 128
#define NTILES (LL / TK)
// fallback tiling (R4-proven)
#define FTQ 128
#define FTK 64
#define FNTILES (LL / FTK)
// 1/sqrt(64) * log2(e), folded into Q at staging (leaky commutes with positive scale)
#define QSCALE 0.18033688011112042f

typedef __bf16 bf16_t;
typedef __bf16 bf16x8 __attribute__((ext_vector_type(8)));
typedef float f32x16 __attribute__((ext_vector_type(16)));

// ---- main kernel LDS: rows padded to odd 16B multiples (proven 0-conflict pattern) ----
struct __align__(16) SMemM {
  bf16_t Qs[TQ][72];    // [lq][d] pre-scaled       9216 B
  bf16_t Ks[TK][72];    // [lk][d]                 18432 B
  bf16_t Vs[DD][136];   // [d][lk]                 17408 B
};
struct __align__(16) SMemME {
  float Oe1[TQ][65];    // partial O, quarters 0+1
  float Oe2[TQ][65];    // partial O, quarters 2+3
};
union __align__(16) SMemMU { SMemM a; SMemME e; };

// ---- fallback LDS (R4 dims) ----
struct __align__(16) SMemF {
  bf16_t Qs[FTQ][72];
  bf16_t Ks[FTK][72];
  bf16_t Vs[DD][72];
};
union __align__(16) SMemFU { SMemF a; float Oe[FTQ][65]; };

// ================= fused prepass: K -> bf16 [head][l][d], V -> bf16 (same layout) ========
__global__ __launch_bounds__(256)
void prep(const float* __restrict__ k, const float* __restrict__ v,
          bf16_t* __restrict__ Kt, bf16_t* __restrict__ Vb) {
  const int bid = blockIdx.x;
  const int tid = threadIdx.x;
  if (bid < 1024) {
    // K transpose+convert: block = (head, 64-l tile); no LDS round-trip.
    const int head = bid >> 5;
    const int l0   = (bid & 31) * 64;
    const float* sp = k + (size_t)head * DD * LL;
    bf16_t* dp = Kt + ((size_t)head * LL + l0) * DD;
    const int lk = tid & 63;
    const int dg = (tid >> 6) * 8;   // 0,8,16,24
    for (int rep = 0; rep < 2; ++rep) {
      const int d0 = dg + rep * 32;
      bf16x8 pk;
      for (int j = 0; j < 8; ++j)   // coalesced: lanes read consecutive l per d-row
        pk[j] = (bf16_t)sp[(size_t)(d0 + j) * LL + l0 + lk];
      *(bf16x8*)(dp + (size_t)lk * DD + d0) = pk;
    }
  } else {
    // V elementwise convert, layout preserved
    size_t i = ((size_t)(bid - 1024) * 256 + tid) * 8;
    float4 a = *(const float4*)(v + i);
    float4 b = *(const float4*)(v + i + 4);
    bf16x8 p;
    p[0] = (bf16_t)a.x; p[1] = (bf16_t)a.y; p[2] = (bf16_t)a.z; p[3] = (bf16_t)a.w;
    p[4] = (bf16_t)b.x; p[5] = (bf16_t)b.y; p[6] = (bf16_t)b.z; p[7] = (bf16_t)b.w;
    *(bf16x8*)(Vb + i) = p;
  }
}

// ================= main: TQ=64, TK=128, 8 waves = 2 lq-strips x 4 lk-quarters ============
__global__ __launch_bounds__(NTHREADS, 4)
void attn_main(const float* __restrict__ q, const bf16_t* __restrict__ Kt,
               const bf16_t* __restrict__ Vb, float* __restrict__ out) {
  __shared__ SMemMU sm;
  __shared__ float rsA[TQ], rsB[TQ];
  const int tid  = threadIdx.x;
  const int w    = tid >> 6;
  const int lane = tid & 63;
  const int l31  = lane & 31;
  const int hh   = lane >> 5;
  const int strip = w & 1;          // lq strip (32 rows of 64)
  const int quart = w >> 1;         // lk quarter (32 of 128)
  const int wbase = strip * 32;
  const int lkh   = quart * 32;
  const int head = blockIdx.y;
  const int q0   = blockIdx.x * TQ;
  const float*  qp = q  + (size_t)head * DD * LL;
  const bf16_t* kp = Kt + (size_t)head * LL * DD;   // [l][d]
  const bf16_t* vp = Vb + (size_t)head * DD * LL;   // [d][l]

  // ---- stage Q transposed + scaled once (fp32 source, coalesced per d-row) ----
  {
    const int lq = tid & 63;
    const int d0 = (tid >> 6) * 8;
    const float* src = qp + q0 + lq;
    bf16x8 pk;
    for (int j = 0; j < 8; ++j)
      pk[j] = (bf16_t)(src[(size_t)(d0 + j) * LL] * QSCALE);
    *(bf16x8*)&sm.a.Qs[lq][d0] = pk;
  }

  // per-tile staging coords: K 2 b128, V 2 b128 per thread
  const int klk  = tid & 127;        // K row lk
  const int kd0  = (tid >> 7) * 16;  // K 16-d range
  const int vd   = tid >> 3;         // V row d
  const int vc16 = (tid & 7) * 16;   // V 16-lk range

  // ---- prefetch tile 0 ----
  bf16x8 kr0 = *(const bf16x8*)(kp + (size_t)klk * DD + kd0);
  bf16x8 kr1 = *(const bf16x8*)(kp + (size_t)klk * DD + kd0 + 8);
  bf16x8 vr0 = *(const bf16x8*)(vp + (size_t)vd * LL + vc16);
  bf16x8 vr1 = *(const bf16x8*)(vp + (size_t)vd * LL + vc16 + 8);

  __syncthreads();   // Q staged
  bf16x8 bq[4];
  for (int kk = 0; kk < 4; ++kk)
    bq[kk] = *(const bf16x8*)&sm.a.Qs[wbase + l31][kk * 16 + 8 * hh];

  f32x16 oacc[2];
  for (int dt = 0; dt < 2; ++dt)
    for (int r = 0; r < 16; ++r) oacc[dt][r] = 0.f;
  float rsum = 0.f;

  for (int t = 0; t < NTILES; ++t) {
    __syncthreads();  // prior tile's Ks/Vs reads done
    *(bf16x8*)&sm.a.Ks[klk][kd0]      = kr0;
    *(bf16x8*)&sm.a.Ks[klk][kd0 + 8]  = kr1;
    *(bf16x8*)&sm.a.Vs[vd][vc16]      = vr0;
    *(bf16x8*)&sm.a.Vs[vd][vc16 + 8]  = vr1;
    __syncthreads();

    if (t + 1 < NTILES) {
      const int lk0n = (t + 1) * TK;
      kr0 = *(const bf16x8*)(kp + (size_t)(lk0n + klk) * DD + kd0);
      kr1 = *(const bf16x8*)(kp + (size_t)(lk0n + klk) * DD + kd0 + 8);
      vr0 = *(const bf16x8*)(vp + (size_t)vd * LL + lk0n + vc16);
      vr1 = *(const bf16x8*)(vp + (size_t)vd * LL + lk0n + vc16 + 8);
    }

    // ---- S^T = K^T Q over this wave's lk quarter ----
    f32x16 st;
    for (int r = 0; r < 16; ++r) st[r] = 0.f;
    for (int kk = 0; kk < 4; ++kk) {
      bf16x8 ak = *(const bf16x8*)&sm.a.Ks[lkh + l31][kk * 16 + 8 * hh];
      st = __builtin_amdgcn_mfma_f32_32x32x16_bf16(ak, bq[kk], st, 0, 0, 0);
    }

    // ---- leaky + exp2 in registers; pack pairs ----
    unsigned pb[8];
    for (int r = 0; r < 16; ++r) {
      float s = st[r];
      s = fmaxf(s, 0.01f * s);
      float p = __builtin_amdgcn_exp2f(s);
      rsum += p;
      st[r] = p;
    }
    for (int qq = 0; qq < 8; ++qq) {
      union { bf16_t b[2]; unsigned u; } pk;
      pk.b[0] = (bf16_t)st[2 * qq];
      pk.b[1] = (bf16_t)st[2 * qq + 1];
      pb[qq] = pk.u;
    }

    // ---- PV over this wave's lk quarter: A built via one cross-half exchange ----
    for (int kk2 = 0; kk2 < 2; ++kk2) {
      unsigned l0 = pb[4 * kk2 + 0], l1 = pb[4 * kk2 + 1];
      unsigned l2 = pb[4 * kk2 + 2], l3 = pb[4 * kk2 + 3];
      unsigned s0 = hh ? l0 : l2;
      unsigned s1 = hh ? l1 : l3;
      unsigned f0 = (unsigned)__shfl_xor((int)s0, 32);
      unsigned f1 = (unsigned)__shfl_xor((int)s1, 32);
      union { unsigned u[4]; bf16x8 v; } ap;
      ap.u[0] = hh ? f0 : l0;
      ap.u[1] = hh ? f1 : l1;
      ap.u[2] = hh ? l2 : f0;
      ap.u[3] = hh ? l3 : f1;
      const int lkb = lkh + kk2 * 16 + 8 * hh;
      for (int dt = 0; dt < 2; ++dt) {
        bf16x8 bv = *(const bf16x8*)&sm.a.Vs[dt * 32 + l31][lkb];
        oacc[dt] = __builtin_amdgcn_mfma_f32_32x32x16_bf16(ap.v, bv, oacc[dt], 0, 0, 0);
      }
    }
  }

  // ---- epilogue: combine 4 lk-quarter partials (additive; m fixed at 0) ----
  float rtot = rsum + __shfl_xor(rsum, 32);
  __syncthreads();                            // compute LDS reads done; union safe
  if (quart == 0) {
    rsA[wbase + l31] = rtot;
    for (int r = 0; r < 16; ++r) {
      int row = (r & 3) + 8 * (r >> 2) + 4 * hh;
      for (int dt = 0; dt < 2; ++dt)
        sm.e.Oe1[wbase + row][dt * 32 + l31] = oacc[dt][r];
    }
  } else if (quart == 2) {
    rsB[wbase + l31] = rtot;
    for (int r = 0; r < 16; ++r) {
      int row = (r & 3) + 8 * (r >> 2) + 4 * hh;
      for (int dt = 0; dt < 2; ++dt)
        sm.e.Oe2[wbase + row][dt * 32 + l31] = oacc[dt][r];
    }
  }
  __syncthreads();
  if (quart == 1) {
    rsA[wbase + l31] += rtot;   // both hh halves write identical value: benign
    for (int r = 0; r < 16; ++r) {
      int row = (r & 3) + 8 * (r >> 2) + 4 * hh;
      for (int dt = 0; dt < 2; ++dt)
        sm.e.Oe1[wbase + row][dt * 32 + l31] += oacc[dt][r];
    }
  } else if (quart == 3) {
    rsB[wbase + l31] += rtot;
    for (int r = 0; r < 16; ++r) {
      int row = (r & 3) + 8 * (r >> 2) + 4 * hh;
      for (int dt = 0; dt < 2; ++dt)
        sm.e.Oe2[wbase + row][dt * 32 + l31] += oacc[dt][r];
    }
  }
  __syncthreads();
  if (tid < TQ) rsA[tid] = 1.0f / (rsA[tid] + rsB[tid]);
  __syncthreads();
  float* op = out + (size_t)head * DD * LL + q0;
  for (int i = 0; i < 8; ++i) {
    int idx = tid + NTHREADS * i;   // 0..4095
    int d   = idx >> 6;
    int lq  = idx & 63;
    op[(size_t)d * LL + lq] = (sm.e.Oe1[lq][d] + sm.e.Oe2[lq][d]) * rsA[lq];
  }
}

// ================= fallback (R4-proven): fp32 inputs, in-kernel convert ==================
__global__ __launch_bounds__(NTHREADS, 4)
void attn_flash_fb(const float* __restrict__ q, const float* __restrict__ k,
                   const float* __restrict__ v, float* __restrict__ out) {
  __shared__ SMemFU sm;
  __shared__ float rs1[FTQ];
  const int tid  = threadIdx.x;
  const int w    = tid >> 6;
  const int lane = tid & 63;
  const int l31  = lane & 31;
  const int hh   = lane >> 5;
  const int strip = w & 3;
  const int half  = w >> 2;
  const int wbase = strip * 32;
  const int lkh   = half * 32;
  const int head = blockIdx.y;
  const int q0   = blockIdx.x * FTQ;
  const size_t hoff = (size_t)head * DD * LL;
  const float* qp = q + hoff;
  const float* kp = k + hoff;
  const float* vp = v + hoff;
  {
    int lq  = tid & 127;
    int d0q = (tid >> 7) * 16;
    const float* src = qp + q0 + lq;
    for (int g = 0; g < 2; ++g) {
      bf16x8 pk;
      for (int j = 0; j < 8; ++j)
        pk[j] = (bf16_t)(src[(size_t)(d0q + g * 8 + j) * LL] * QSCALE);
      *(bf16x8*)&sm.a.Qs[lq][d0q + g * 8] = pk;
    }
  }
  const int klk = tid & 63;
  const int kd0 = (tid >> 6) * 8;
  const int vd  = tid >> 3;
  const int vc8 = (tid & 7) * 8;
  float  kreg[8];
  float4 vreg[2];
  {
    const float* ks = kp + klk;
    for (int j = 0; j < 8; ++j) kreg[j] = ks[(size_t)(kd0 + j) * LL];
    vreg[0] = *(const float4*)(vp + (size_t)vd * LL + vc8);
    vreg[1] = *(const float4*)(vp + (size_t)vd * LL + vc8 + 4);
  }
  __syncthreads();
  bf16x8 bq[4];
  for (int kk = 0; kk < 4; ++kk)
    bq[kk] = *(const bf16x8*)&sm.a.Qs[wbase + l31][kk * 16 + 8 * hh];
  f32x16 oacc[2];
  for (int dt = 0; dt < 2; ++dt)
    for (int r = 0; r < 16; ++r) oacc[dt][r] = 0.f;
  float rsum = 0.f;
  for (int t = 0; t < FNTILES; ++t) {
    __syncthreads();
    {
      bf16x8 pk;
      for (int j = 0; j < 8; ++j) pk[j] = (bf16_t)kreg[j];
      *(bf16x8*)&sm.a.Ks[klk][kd0] = pk;
      bf16x8 pv;
      pv[0] = (bf16_t)vreg[0].x; pv[1] = (bf16_t)vreg[0].y;
      pv[2] = (bf16_t)vreg[0].z; pv[3] = (bf16_t)vreg[0].w;
      pv[4] = (bf16_t)vreg[1].x; pv[5] = (bf16_t)vreg[1].y;
      pv[6] = (bf16_t)vreg[1].z; pv[7] = (bf16_t)vreg[1].w;
      *(bf16x8*)&sm.a.Vs[vd][vc8] = pv;
    }
    __syncthreads();
    if (t + 1 < FNTILES) {
      const int lk0n = (t + 1) * FTK;
      const float* ks = kp + lk0n + klk;
      for (int j = 0; j < 8; ++j) kreg[j] = ks[(size_t)(kd0 + j) * LL];
      vreg[0] = *(const float4*)(vp + (size_t)vd * LL + lk0n + vc8);
      vreg[1] = *(const float4*)(vp + (size_t)vd * LL + lk0n + vc8 + 4);
    }
    f32x16 st;
    for (int r = 0; r < 16; ++r) st[r] = 0.f;
    for (int kk = 0; kk < 4; ++kk) {
      bf16x8 ak = *(const bf16x8*)&sm.a.Ks[lkh + l31][kk * 16 + 8 * hh];
      st = __builtin_amdgcn_mfma_f32_32x32x16_bf16(ak, bq[kk], st, 0, 0, 0);
    }
    unsigned pb[8];
    for (int r = 0; r < 16; ++r) {
      float s = st[r];
      s = fmaxf(s, 0.01f * s);
      float p = __builtin_amdgcn_exp2f(s);
      rsum += p;
      st[r] = p;
    }
    for (int qq = 0; qq < 8; ++qq) {
      union { bf16_t b[2]; unsigned u; } pk;
      pk.b[0] = (bf16_t)st[2 * qq];
      pk.b[1] = (bf16_t)st[2 * qq + 1];
      pb[qq] = pk.u;
    }
    for (int kk2 = 0; kk2 < 2; ++kk2) {
      unsigned l0 = pb[4 * kk2 + 0], l1 = pb[4 * kk2 + 1];
      unsigned l2 = pb[4 * kk2 + 2], l3 = pb[4 * kk2 + 3];
      unsigned s0 = hh ? l0 : l2;
      unsigned s1 = hh ? l1 : l3;
      unsigned f0 = (unsigned)__shfl_xor((int)s0, 32);
      unsigned f1 = (unsigned)__shfl_xor((int)s1, 32);
      union { unsigned u[4]; bf16x8 v; } ap;
      ap.u[0] = hh ? f0 : l0;
      ap.u[1] = hh ? f1 : l1;
      ap.u[2] = hh ? l2 : f0;
      ap.u[3] = hh ? l3 : f1;
      const int lkb = lkh + kk2 * 16 + 8 * hh;
      for (int dt = 0; dt < 2; ++dt) {
        bf16x8 bv = *(const bf16x8*)&sm.a.Vs[dt * 32 + l31][lkb];
        oacc[dt] = __builtin_amdgcn_mfma_f32_32x32x16_bf16(ap.v, bv, oacc[dt], 0, 0, 0);
      }
    }
  }
  float rtot = rsum + __shfl_xor(rsum, 32);
  __syncthreads();
  if (half == 1) {
    rs1[wbase + l31] = rtot;
    for (int r = 0; r < 16; ++r) {
      int row = (r & 3) + 8 * (r >> 2) + 4 * hh;
      for (int dt = 0; dt < 2; ++dt)
        sm.Oe[wbase + row][dt * 32 + l31] = oacc[dt][r];
    }
  }
  __syncthreads();
  if (half == 0) {
    float tot = rtot + rs1[wbase + l31];
    rs1[wbase + l31] = 1.0f / tot;
    float inv[16];
    for (int r = 0; r < 16; ++r) {
      int row = (r & 3) + 8 * (r >> 2) + 4 * hh;
      inv[r] = rs1[wbase + row];
    }
    for (int r = 0; r < 16; ++r) {
      int row = (r & 3) + 8 * (r >> 2) + 4 * hh;
      for (int dt = 0; dt < 2; ++dt) {
        int col = dt * 32 + l31;
        sm.Oe[wbase + row][col] = (oacc[dt][r] + sm.Oe[wbase + row][col]) * inv[r];
      }
    }
  }
  __syncthreads();
  float* op = out + hoff + q0;
  for (int i = 0; i < 16; ++i) {
    int idx = tid + NTHREADS * i;
    int d   = idx >> 7;
    int lq  = idx & 127;
    op[(size_t)d * LL + lq] = sm.Oe[lq][d];
  }
}

extern "C" void kernel_launch(void* const* d_in, const int* in_sizes, int n_in,
                              void* d_out, int out_size, void* d_ws, size_t ws_size,
                              hipStream_t stream) {
  const float* q = (const float*)d_in[0];
  const float* k = (const float*)d_in[1];
  const float* v = (const float*)d_in[2];
  float* out = (float*)d_out;
  const size_t tsz  = (size_t)NHEADS * LL * DD;       // 4,194,304 elems/tensor
  const size_t need = 2 * tsz * sizeof(bf16_t);       // 16,777,216 B (K + V bf16)
  if (ws_size >= need) {
    bf16_t* Kt = (bf16_t*)d_ws;
    bf16_t* Vb = Kt + tsz;
    prep<<<1024 + 2048, 256, 0, stream>>>(k, v, Kt, Vb);
    dim3 grid(LL / TQ, NHEADS);   // 32 x 32 = 1024 blocks
    attn_main<<<grid, NTHREADS, 0, stream>>>(q, Kt, Vb, out);
  } else {
    dim3 grid(LL / FTQ, NHEADS);  // 16 x 32
    attn_flash_fb<<<grid, NTHREADS, 0, stream>>>(q, k, v, out);
  }
}

// Round 9
// 149.100 us; speedup vs baseline: 1.0425x; 1.0425x over previous
//
#include <hip/hip_runtime.h>
#include <math.h>

#define DD 64
#define LL 2048
#define NHEADS 32
#define NTHREADS 512
// main kernel tiling (R7-proven best)
#define TQ 128
#define TK 64
#define NTILES (LL / TK)
// fallback tiling (R4-proven)
#define FTQ 128
#define FTK 64
#define FNTILES (LL / FTK)
// 1/sqrt(64) * log2(e), folded into Q at staging (leaky commutes with positive scale)
#define QSCALE 0.18033688011112042f

typedef __bf16 bf16_t;
typedef __bf16 bf16x8 __attribute__((ext_vector_type(8)));
typedef float f32x16 __attribute__((ext_vector_type(16)));

// ---- main kernel LDS: rows padded to 72 elems (144B = 9*16B, proven 0-conflict) ----
struct __align__(16) SMemM {
  bf16_t Qs[TQ][72];        // [lq][d] pre-scaled             18432 B
  bf16_t Ks[2][TK][72];     // [buf][lk][d] double-buffered   18432 B
  bf16_t Vs[2][DD][72];     // [buf][d][lk] double-buffered   18432 B
};
union __align__(16) SMemMU {
  SMemM a;
  float Oe[TQ][65];         // epilogue combine/transpose buffer (fp32)
};

// ---- fallback LDS (R4 dims) ----
struct __align__(16) SMemF {
  bf16_t Qs[FTQ][72];
  bf16_t Ks[FTK][72];
  bf16_t Vs[DD][72];
};
union __align__(16) SMemFU { SMemF a; float Oe[FTQ][65]; };

// ================= fused prepass: K -> bf16 [head][l][d], V -> bf16 (layout kept) ========
__global__ __launch_bounds__(256)
void prep(const float* __restrict__ k, const float* __restrict__ v,
          bf16_t* __restrict__ Kt, bf16_t* __restrict__ Vb) {
  const int bid = blockIdx.x;
  const int tid = threadIdx.x;
  if (bid < 1024) {
    // K transpose+convert: block = (head, 64-l tile); no LDS round-trip.
    const int head = bid >> 5;
    const int l0   = (bid & 31) * 64;
    const float* sp = k + (size_t)head * DD * LL;
    bf16_t* dp = Kt + ((size_t)head * LL + l0) * DD;
    const int lk = tid & 63;
    const int dg = (tid >> 6) * 8;   // 0,8,16,24
    for (int rep = 0; rep < 2; ++rep) {
      const int d0 = dg + rep * 32;
      bf16x8 pk;
      for (int j = 0; j < 8; ++j)   // coalesced: lanes read consecutive l per d-row
        pk[j] = (bf16_t)sp[(size_t)(d0 + j) * LL + l0 + lk];
      *(bf16x8*)(dp + (size_t)lk * DD + d0) = pk;
    }
  } else {
    // V elementwise convert, layout preserved
    size_t i = ((size_t)(bid - 1024) * 256 + tid) * 8;
    float4 a = *(const float4*)(v + i);
    float4 b = *(const float4*)(v + i + 4);
    bf16x8 p;
    p[0] = (bf16_t)a.x; p[1] = (bf16_t)a.y; p[2] = (bf16_t)a.z; p[3] = (bf16_t)a.w;
    p[4] = (bf16_t)b.x; p[5] = (bf16_t)b.y; p[6] = (bf16_t)b.z; p[7] = (bf16_t)b.w;
    *(bf16x8*)(Vb + i) = p;
  }
}

// ================= main: TQ=128, TK=64, dbuf LDS, one barrier/tile =======================
__global__ __launch_bounds__(NTHREADS, 4)
void attn_main(const float* __restrict__ q, const bf16_t* __restrict__ Kt,
               const bf16_t* __restrict__ Vb, float* __restrict__ out) {
  __shared__ SMemMU sm;
  __shared__ float rs1[TQ];
  const int tid  = threadIdx.x;
  const int w    = tid >> 6;
  const int lane = tid & 63;
  const int l31  = lane & 31;
  const int hh   = lane >> 5;
  const int strip = w & 3;          // lq strip (32 rows)
  const int half  = w >> 2;         // lk half 0/1
  const int wbase = strip * 32;
  const int lkh   = half * 32;
  const int head = blockIdx.y;
  const int q0   = blockIdx.x * TQ;
  const float*  qp = q  + (size_t)head * DD * LL;
  const bf16_t* kp = Kt + (size_t)head * LL * DD;   // [l][d]
  const bf16_t* vp = Vb + (size_t)head * DD * LL;   // [d][l]

  // per-tile staging coords (one b128 load + one b128 write each for K and V)
  const int klk = tid & 63;             // K row lk
  const int kd0 = (tid >> 6) * 8;       // K 8-d range
  const int vd  = tid >> 3;             // V row d
  const int vc8 = (tid & 7) * 8;        // V 8-lk range

  // ---- prefetch tile 0 ----
  bf16x8 kr = *(const bf16x8*)(kp + (size_t)klk * DD + kd0);
  bf16x8 vr = *(const bf16x8*)(vp + (size_t)vd * LL + vc8);

  // ---- stage Q transposed + scaled once (fp32 source, coalesced per d-row) ----
  {
    const int lq = tid & 127;
    const int d0 = (tid >> 7) * 16;
    const float* src = qp + q0 + lq;
    bf16x8 p0, p1;
    for (int j = 0; j < 8; ++j) {
      p0[j] = (bf16_t)(src[(size_t)(d0 + j) * LL] * QSCALE);
      p1[j] = (bf16_t)(src[(size_t)(d0 + 8 + j) * LL] * QSCALE);
    }
    *(bf16x8*)&sm.a.Qs[lq][d0]     = p0;
    *(bf16x8*)&sm.a.Qs[lq][d0 + 8] = p1;
  }
  __syncthreads();   // Q staged

  bf16x8 bq[4];
  for (int kk = 0; kk < 4; ++kk)
    bq[kk] = *(const bf16x8*)&sm.a.Qs[wbase + l31][kk * 16 + 8 * hh];

  f32x16 oacc[2];
  for (int dt = 0; dt < 2; ++dt)
    for (int r = 0; r < 16; ++r) oacc[dt][r] = 0.f;
  float rsum = 0.f;

  // commit tile 0 to buffer 0; prefetch tile 1
  *(bf16x8*)&sm.a.Ks[0][klk][kd0] = kr;
  *(bf16x8*)&sm.a.Vs[0][vd][vc8]  = vr;
  kr = *(const bf16x8*)(kp + (size_t)(TK + klk) * DD + kd0);
  vr = *(const bf16x8*)(vp + (size_t)vd * LL + TK + vc8);
  __syncthreads();   // buffer 0 ready

  auto compute_tile = [&](int buf) {
    // ---- S^T = K^T Q over this wave's lk half ----
    f32x16 st;
    for (int r = 0; r < 16; ++r) st[r] = 0.f;
    for (int kk = 0; kk < 4; ++kk) {
      bf16x8 ak = *(const bf16x8*)&sm.a.Ks[buf][lkh + l31][kk * 16 + 8 * hh];
      st = __builtin_amdgcn_mfma_f32_32x32x16_bf16(ak, bq[kk], st, 0, 0, 0);
    }
    // ---- leaky + exp2 in registers; pack pairs ----
    unsigned pb[8];
    for (int r = 0; r < 16; ++r) {
      float s = st[r];
      s = fmaxf(s, 0.01f * s);
      float p = __builtin_amdgcn_exp2f(s);
      rsum += p;
      st[r] = p;
    }
    for (int qq = 0; qq < 8; ++qq) {
      union { bf16_t b[2]; unsigned u; } pk;
      pk.b[0] = (bf16_t)st[2 * qq];
      pk.b[1] = (bf16_t)st[2 * qq + 1];
      pb[qq] = pk.u;
    }
    // ---- PV: A built via one cross-half exchange ----
    for (int kk2 = 0; kk2 < 2; ++kk2) {
      unsigned l0 = pb[4 * kk2 + 0], l1 = pb[4 * kk2 + 1];
      unsigned l2 = pb[4 * kk2 + 2], l3 = pb[4 * kk2 + 3];
      unsigned s0 = hh ? l0 : l2;
      unsigned s1 = hh ? l1 : l3;
      unsigned f0 = (unsigned)__shfl_xor((int)s0, 32);
      unsigned f1 = (unsigned)__shfl_xor((int)s1, 32);
      union { unsigned u[4]; bf16x8 v; } ap;
      ap.u[0] = hh ? f0 : l0;
      ap.u[1] = hh ? f1 : l1;
      ap.u[2] = hh ? l2 : f0;
      ap.u[3] = hh ? l3 : f1;
      const int lkb = lkh + kk2 * 16 + 8 * hh;
      for (int dt = 0; dt < 2; ++dt) {
        bf16x8 bv = *(const bf16x8*)&sm.a.Vs[buf][dt * 32 + l31][lkb];
        oacc[dt] = __builtin_amdgcn_mfma_f32_32x32x16_bf16(ap.v, bv, oacc[dt], 0, 0, 0);
      }
    }
  };

  for (int i = 0; i < NTILES / 2; ++i) {
    // regs hold tile 2i+1; buffer A(=0) holds tile 2i (barriered)
    *(bf16x8*)&sm.a.Ks[1][klk][kd0] = kr;   // B free (barrier after its last read)
    *(bf16x8*)&sm.a.Vs[1][vd][vc8]  = vr;
    {
      const int tn = (2 * i + 2 < NTILES) ? (2 * i + 2) : (NTILES - 1);
      kr = *(const bf16x8*)(kp + (size_t)(tn * TK + klk) * DD + kd0);
      vr = *(const bf16x8*)(vp + (size_t)vd * LL + tn * TK + vc8);
    }
    compute_tile(0);
    __syncthreads();   // B ready; A reads done

    *(bf16x8*)&sm.a.Ks[0][klk][kd0] = kr;
    *(bf16x8*)&sm.a.Vs[0][vd][vc8]  = vr;
    {
      const int tn = (2 * i + 3 < NTILES) ? (2 * i + 3) : (NTILES - 1);
      kr = *(const bf16x8*)(kp + (size_t)(tn * TK + klk) * DD + kd0);
      vr = *(const bf16x8*)(vp + (size_t)vd * LL + tn * TK + vc8);
    }
    compute_tile(1);
    __syncthreads();   // A ready; B reads done
  }

  // ---- epilogue: combine lk-half pairs, normalize, transpose, store (R7 verbatim) ----
  float rtot = rsum + __shfl_xor(rsum, 32);
  // loop ended on a barrier: all compute LDS reads done; union safe
  if (half == 1) {
    rs1[wbase + l31] = rtot;
    for (int r = 0; r < 16; ++r) {
      int row = (r & 3) + 8 * (r >> 2) + 4 * hh;
      for (int dt = 0; dt < 2; ++dt)
        sm.Oe[wbase + row][dt * 32 + l31] = oacc[dt][r];
    }
  }
  __syncthreads();
  if (half == 0) {
    float tot = rtot + rs1[wbase + l31];
    rs1[wbase + l31] = 1.0f / tot;
    float inv[16];
    for (int r = 0; r < 16; ++r) {
      int row = (r & 3) + 8 * (r >> 2) + 4 * hh;
      inv[r] = rs1[wbase + row];
    }
    for (int r = 0; r < 16; ++r) {
      int row = (r & 3) + 8 * (r >> 2) + 4 * hh;
      for (int dt = 0; dt < 2; ++dt) {
        int col = dt * 32 + l31;
        sm.Oe[wbase + row][col] = (oacc[dt][r] + sm.Oe[wbase + row][col]) * inv[r];
      }
    }
  }
  __syncthreads();
  float* op = out + (size_t)head * DD * LL + q0;
  for (int i = 0; i < 16; ++i) {
    int idx = tid + NTHREADS * i;
    int d   = idx >> 7;
    int lq  = idx & 127;
    op[(size_t)d * LL + lq] = sm.Oe[lq][d];
  }
}

// ================= fallback (R4-proven): fp32 inputs, in-kernel convert ==================
__global__ __launch_bounds__(NTHREADS, 4)
void attn_flash_fb(const float* __restrict__ q, const float* __restrict__ k,
                   const float* __restrict__ v, float* __restrict__ out) {
  __shared__ SMemFU sm;
  __shared__ float rs1[FTQ];
  const int tid  = threadIdx.x;
  const int w    = tid >> 6;
  const int lane = tid & 63;
  const int l31  = lane & 31;
  const int hh   = lane >> 5;
  const int strip = w & 3;
  const int half  = w >> 2;
  const int wbase = strip * 32;
  const int lkh   = half * 32;
  const int head = blockIdx.y;
  const int q0   = blockIdx.x * FTQ;
  const size_t hoff = (size_t)head * DD * LL;
  const float* qp = q + hoff;
  const float* kp = k + hoff;
  const float* vp = v + hoff;
  {
    int lq  = tid & 127;
    int d0q = (tid >> 7) * 16;
    const float* src = qp + q0 + lq;
    for (int g = 0; g < 2; ++g) {
      bf16x8 pk;
      for (int j = 0; j < 8; ++j)
        pk[j] = (bf16_t)(src[(size_t)(d0q + g * 8 + j) * LL] * QSCALE);
      *(bf16x8*)&sm.a.Qs[lq][d0q + g * 8] = pk;
    }
  }
  const int klk = tid & 63;
  const int kd0 = (tid >> 6) * 8;
  const int vd  = tid >> 3;
  const int vc8 = (tid & 7) * 8;
  float  kreg[8];
  float4 vreg[2];
  {
    const float* ks = kp + klk;
    for (int j = 0; j < 8; ++j) kreg[j] = ks[(size_t)(kd0 + j) * LL];
    vreg[0] = *(const float4*)(vp + (size_t)vd * LL + vc8);
    vreg[1] = *(const float4*)(vp + (size_t)vd * LL + vc8 + 4);
  }
  __syncthreads();
  bf16x8 bq[4];
  for (int kk = 0; kk < 4; ++kk)
    bq[kk] = *(const bf16x8*)&sm.a.Qs[wbase + l31][kk * 16 + 8 * hh];
  f32x16 oacc[2];
  for (int dt = 0; dt < 2; ++dt)
    for (int r = 0; r < 16; ++r) oacc[dt][r] = 0.f;
  float rsum = 0.f;
  for (int t = 0; t < FNTILES; ++t) {
    __syncthreads();
    {
      bf16x8 pk;
      for (int j = 0; j < 8; ++j) pk[j] = (bf16_t)kreg[j];
      *(bf16x8*)&sm.a.Ks[klk][kd0] = pk;
      bf16x8 pv;
      pv[0] = (bf16_t)vreg[0].x; pv[1] = (bf16_t)vreg[0].y;
      pv[2] = (bf16_t)vreg[0].z; pv[3] = (bf16_t)vreg[0].w;
      pv[4] = (bf16_t)vreg[1].x; pv[5] = (bf16_t)vreg[1].y;
      pv[6] = (bf16_t)vreg[1].z; pv[7] = (bf16_t)vreg[1].w;
      *(bf16x8*)&sm.a.Vs[vd][vc8] = pv;
    }
    __syncthreads();
    if (t + 1 < FNTILES) {
      const int lk0n = (t + 1) * FTK;
      const float* ks = kp + lk0n + klk;
      for (int j = 0; j < 8; ++j) kreg[j] = ks[(size_t)(kd0 + j) * LL];
      vreg[0] = *(const float4*)(vp + (size_t)vd * LL + lk0n + vc8);
      vreg[1] = *(const float4*)(vp + (size_t)vd * LL + lk0n + vc8 + 4);
    }
    f32x16 st;
    for (int r = 0; r < 16; ++r) st[r] = 0.f;
    for (int kk = 0; kk < 4; ++kk) {
      bf16x8 ak = *(const bf16x8*)&sm.a.Ks[lkh + l31][kk * 16 + 8 * hh];
      st = __builtin_amdgcn_mfma_f32_32x32x16_bf16(ak, bq[kk], st, 0, 0, 0);
    }
    unsigned pb[8];
    for (int r = 0; r < 16; ++r) {
      float s = st[r];
      s = fmaxf(s, 0.01f * s);
      float p = __builtin_amdgcn_exp2f(s);
      rsum += p;
      st[r] = p;
    }
    for (int qq = 0; qq < 8; ++qq) {
      union { bf16_t b[2]; unsigned u; } pk;
      pk.b[0] = (bf16_t)st[2 * qq];
      pk.b[1] = (bf16_t)st[2 * qq + 1];
      pb[qq] = pk.u;
    }
    for (int kk2 = 0; kk2 < 2; ++kk2) {
      unsigned l0 = pb[4 * kk2 + 0], l1 = pb[4 * kk2 + 1];
      unsigned l2 = pb[4 * kk2 + 2], l3 = pb[4 * kk2 + 3];
      unsigned s0 = hh ? l0 : l2;
      unsigned s1 = hh ? l1 : l3;
      unsigned f0 = (unsigned)__shfl_xor((int)s0, 32);
      unsigned f1 = (unsigned)__shfl_xor((int)s1, 32);
      union { unsigned u[4]; bf16x8 v; } ap;
      ap.u[0] = hh ? f0 : l0;
      ap.u[1] = hh ? f1 : l1;
      ap.u[2] = hh ? l2 : f0;
      ap.u[3] = hh ? l3 : f1;
      const int lkb = lkh + kk2 * 16 + 8 * hh;
      for (int dt = 0; dt < 2; ++dt) {
        bf16x8 bv = *(const bf16x8*)&sm.a.Vs[dt * 32 + l31][lkb];
        oacc[dt] = __builtin_amdgcn_mfma_f32_32x32x16_bf16(ap.v, bv, oacc[dt], 0, 0, 0);
      }
    }
  }
  float rtot = rsum + __shfl_xor(rsum, 32);
  __syncthreads();
  if (half == 1) {
    rs1[wbase + l31] = rtot;
    for (int r = 0; r < 16; ++r) {
      int row = (r & 3) + 8 * (r >> 2) + 4 * hh;
      for (int dt = 0; dt < 2; ++dt)
        sm.Oe[wbase + row][dt * 32 + l31] = oacc[dt][r];
    }
  }
  __syncthreads();
  if (half == 0) {
    float tot = rtot + rs1[wbase + l31];
    rs1[wbase + l31] = 1.0f / tot;
    float inv[16];
    for (int r = 0; r < 16; ++r) {
      int row = (r & 3) + 8 * (r >> 2) + 4 * hh;
      inv[r] = rs1[wbase + row];
    }
    for (int r = 0; r < 16; ++r) {
      int row = (r & 3) + 8 * (r >> 2) + 4 * hh;
      for (int dt = 0; dt < 2; ++dt) {
        int col = dt * 32 + l31;
        sm.Oe[wbase + row][col] = (oacc[dt][r] + sm.Oe[wbase + row][col]) * inv[r];
      }
    }
  }
  __syncthreads();
  float* op = out + hoff + q0;
  for (int i = 0; i < 16; ++i) {
    int idx = tid + NTHREADS * i;
    int d   = idx >> 7;
    int lq  = idx & 127;
    op[(size_t)d * LL + lq] = sm.Oe[lq][d];
  }
}

extern "C" void kernel_launch(void* const* d_in, const int* in_sizes, int n_in,
                              void* d_out, int out_size, void* d_ws, size_t ws_size,
                              hipStream_t stream) {
  const float* q = (const float*)d_in[0];
  const float* k = (const float*)d_in[1];
  const float* v = (const float*)d_in[2];
  float* out = (float*)d_out;
  const size_t tsz  = (size_t)NHEADS * LL * DD;       // 4,194,304 elems/tensor
  const size_t need = 2 * tsz * sizeof(bf16_t);       // 16,777,216 B (K + V bf16)
  if (ws_size >= need) {
    bf16_t* Kt = (bf16_t*)d_ws;
    bf16_t* Vb = Kt + tsz;
    prep<<<1024 + 2048, 256, 0, stream>>>(k, v, Kt, Vb);
    dim3 grid(LL / TQ, NHEADS);   // 16 x 32 = 512 blocks
    attn_main<<<grid, NTHREADS, 0, stream>>>(q, Kt, Vb, out);
  } else {
    dim3 grid(LL / FTQ, NHEADS);  // 16 x 32
    attn_flash_fb<<<grid, NTHREADS, 0, stream>>>(q, k, v, out);
  }
}